// Round 3
// baseline (159.593 us; speedup 1.0000x reference)
//
#include <hip/hip_runtime.h>

// KAN layer as one fused fp16 MFMA GEMM:
//   out[b,i] = sum_j [ neg*bw*pw + pos*bw + sum_k basis[b,j,k]*sw[i,j]*sc[i,j,k] ]
// A  [2048 x 11264] fp16 : per j, 22 slots = {20 basis (5 nonzero), neg, pos}
// Ct [ 512 x 11264] fp16 : per j, 22 slots = {sw*sc[0..19], bw*pw, bw}   (B^T layout)
// GEMM: 128x128 tiles, mfma_f32_16x16x32_f16, global_load_lds(16B), splitK=16 + f32 atomics.
// R3: LDS XOR swizzle (kill 8-way read conflicts), KSPLIT 8->16 (occupancy 18%->~35%),
//     memset+prep_A+prep_C fused into one dispatch (kill graph-node serialization).
// ws usage: A = 46.1 MB, Ct = 11.5 MB (57.7 MB total).

typedef _Float16 half_t;
typedef __attribute__((ext_vector_type(8))) _Float16 half8;
typedef __attribute__((ext_vector_type(4))) float floatx4;

#define B_DIM   2048
#define J_DIM   512
#define O_DIM   512
#define SLOTS   22
#define K_TOT   (J_DIM * SLOTS)      // 11264
#define MTILE   128
#define NTILE   128
#define BK      32
#define KSPLIT  16
#define KS_LEN  (K_TOT / KSPLIT)     // 704
#define KCH     (KS_LEN / BK)        // 22
#define ZERO_BLKS 64                 // blocks zeroing the 4 MB output

// ---------------------------------------------------------------------------
// Quartic B-spline local basis, uniform knots g_i = -1.5 + i*(3.125/24).
// (Reference quirk: linspace(-1.5, 1.625, 25) -> spacing 3.125/24, NOT 0.125.)
// Matches reference De Boor recursion; m in [3,19]; window k = m-4 .. m,
// entries with k<0 dropped (truncated family, as in the reference).
__device__ __forceinline__ void bspline5(float xc, int& k0, float Nv[5]) {
    const float invS = 7.68f;              // 24/3.125 (exact ratio)
    float u = (xc + 1.5f) * invS;          // knot units
    int m = (int)u;
    m = min(max(m, 3), 19);
    k0 = m - 4;
    Nv[0] = 1.f; Nv[1] = 0.f; Nv[2] = 0.f; Nv[3] = 0.f; Nv[4] = 0.f;
#pragma unroll
    for (int d = 1; d <= 4; ++d) {
        float nw[5];
        float inv_d = 1.0f / (float)d;
#pragma unroll
        for (int r = 0; r < 5; ++r) {
            if (r > d) { nw[r] = 0.f; continue; }
            float kk = (float)(m - d + r);
            float acc = 0.f;
            if (r >= 1) acc += (u - kk) * Nv[r - 1];
            if (r < d)  acc += (kk + (float)(d + 1) - u) * Nv[r];
            nw[r] = acc * inv_d;
        }
#pragma unroll
        for (int r = 0; r < 5; ++r) Nv[r] = nw[r];
    }
}

// ---------------------------------------------------------------------------
// Fused prep: blocks [0,64) zero the output; [64, 64+512) build Ct rows;
// [64+512, 64+512+2048) build A rows. One dispatch -> preps overlap on CUs.
__global__ __launch_bounds__(256) void prep_all(const float* __restrict__ x,
                                                const float* __restrict__ pw,
                                                const float* __restrict__ bw,
                                                const float* __restrict__ sw,
                                                const float* __restrict__ sc,
                                                half_t* __restrict__ A,
                                                half_t* __restrict__ Ct,
                                                float* __restrict__ out) {
    __shared__ half_t rec[J_DIM * SLOTS];  // 22528 B
    int bid = blockIdx.x;
    int t = threadIdx.x;

    if (bid < ZERO_BLKS) {
        // zero 4 MB output: 64 blocks x 256 thr x 16 float4
        float4* o = (float4*)out;
        int base = bid * 4096;
#pragma unroll
        for (int i = 0; i < 16; ++i)
            o[base + i * 256 + t] = make_float4(0.f, 0.f, 0.f, 0.f);
        return;
    }

    if (bid < ZERO_BLKS + O_DIM) {
        // prep_C role: fold spline_weight into coeffs + base slots
        int i = bid - ZERO_BLKS;
#pragma unroll
        for (int jj = 0; jj < 2; ++jj) {
            int j = t + jj * 256;
            size_t ij = (size_t)i * J_DIM + j;
            float s = sw[ij], b = bw[ij], p = pw[ij];
            const float* scp = sc + ij * 20;
            half_t* r = rec + j * SLOTS;
#pragma unroll
            for (int k = 0; k < 20; ++k) r[k] = (half_t)(s * scp[k]);
            r[20] = (half_t)(b * p);
            r[21] = (half_t)b;
        }
        __syncthreads();
        const uint4* src = (const uint4*)rec;
        uint4* dst = (uint4*)(Ct + (size_t)i * K_TOT);
        for (int idx = t; idx < (J_DIM * SLOTS * 2) / 16; idx += 256) dst[idx] = src[idx];
        return;
    }

    // prep_A role: basis record per (b, j)
    int b = bid - ZERO_BLKS - O_DIM;
#pragma unroll
    for (int jj = 0; jj < 2; ++jj) {
        int j = t + jj * 256;
        float xv = x[(size_t)b * J_DIM + j];
        float xc = fminf(fmaxf(xv, -1.f), 1.f);
        float pos = fmaxf(xc, 0.f);
        float neg = xc - pos;
        int k0; float Nv[5];
        bspline5(xc, k0, Nv);
        half_t* r = rec + j * SLOTS;
#pragma unroll
        for (int k = 0; k < 20; ++k) r[k] = (half_t)0.f;
#pragma unroll
        for (int rr = 0; rr < 5; ++rr) {
            int k = k0 + rr;
            if (k >= 0) r[k] = (half_t)Nv[rr];   // k <= 19 guaranteed (k0 <= 15)
        }
        r[20] = (half_t)neg;
        r[21] = (half_t)pos;
    }
    __syncthreads();
    const uint4* src = (const uint4*)rec;
    uint4* dst = (uint4*)(A + (size_t)b * K_TOT);
    for (int i = t; i < (J_DIM * SLOTS * 2) / 16; i += 256) dst[i] = src[i];
}

// ---------------------------------------------------------------------------
// GEMM: Grid (16, 4, 16) = (m-blocks, n-blocks, k-splits), 256 thr.
// LDS layout is XOR-swizzled: LDS(row, quad qs) holds global k-quad
// qg = qs ^ ((row>>1)&3). Applied on the global_load_lds SOURCE address
// (LDS side is hardwired base + lane*16); reads apply the matching XOR.
// 16 lanes of a fragment-read quad then cover all 8 bank-groups 2x -> 2-way
// (free, m136) instead of 8-way.
__global__ __launch_bounds__(256, 4) void gemm_f16(const half_t* __restrict__ A,
                                                   const half_t* __restrict__ Bt,
                                                   float* __restrict__ out) {
    __shared__ half_t As[MTILE * BK];   // 8 KB
    __shared__ half_t Bs[NTILE * BK];   // 8 KB

    int m0 = blockIdx.x * MTILE;
    int n0 = blockIdx.y * NTILE;
    int ks = blockIdx.z * KS_LEN;       // 704*2 B = 16B-aligned

    int t = threadIdx.x;
    int w = t >> 6;          // wave 0..3
    int l = t & 63;
    int wm = w >> 1, wn = w & 1;

    floatx4 acc[4][4] = {};

    int lrow = l >> 2;                            // 0..15: row within 16-row chunk
    int lkof = (((l & 3) ^ ((l >> 3) & 3)) * 8);  // swizzled k-quad source offset

    const half_t* gA = A + (size_t)m0 * K_TOT + ks;
    const half_t* gB = Bt + (size_t)n0 * K_TOT + ks;

    int q = l >> 4;               // 0..3
    int fr = l & 15;              // 0..15
    int qs = (q ^ ((fr >> 1) & 3)) * 8;  // swizzled read offset (elements)

    for (int c = 0; c < KCH; ++c) {
        int kb = c * BK;
#pragma unroll
        for (int n = 0; n < 2; ++n) {
            int r = (w * 2 + n) * 16 + lrow;
            __builtin_amdgcn_global_load_lds(
                (const __attribute__((address_space(1))) unsigned int*)
                    (gA + (size_t)r * K_TOT + kb + lkof),
                (__attribute__((address_space(3))) unsigned int*)
                    (As + (w * 2 + n) * 512),
                16, 0, 0);
            __builtin_amdgcn_global_load_lds(
                (const __attribute__((address_space(1))) unsigned int*)
                    (gB + (size_t)r * K_TOT + kb + lkof),
                (__attribute__((address_space(3))) unsigned int*)
                    (Bs + (w * 2 + n) * 512),
                16, 0, 0);
        }
        __syncthreads();

        half8 af[4], bf[4];
#pragma unroll
        for (int mt = 0; mt < 4; ++mt)
            af[mt] = *(const half8*)(As + (wm * 64 + mt * 16 + fr) * BK + qs);
#pragma unroll
        for (int nt = 0; nt < 4; ++nt)
            bf[nt] = *(const half8*)(Bs + (wn * 64 + nt * 16 + fr) * BK + qs);
#pragma unroll
        for (int mt = 0; mt < 4; ++mt)
#pragma unroll
            for (int nt = 0; nt < 4; ++nt)
                acc[mt][nt] = __builtin_amdgcn_mfma_f32_16x16x32_f16(
                    af[mt], bf[nt], acc[mt][nt], 0, 0, 0);
        __syncthreads();
    }

    // epilogue: C/D layout col = lane&15, row = (lane>>4)*4 + reg (m89-verified)
#pragma unroll
    for (int mt = 0; mt < 4; ++mt)
#pragma unroll
        for (int nt = 0; nt < 4; ++nt) {
            int rr = m0 + wm * 64 + mt * 16 + q * 4;
            int cc = n0 + wn * 64 + nt * 16 + fr;
#pragma unroll
            for (int r = 0; r < 4; ++r)
                atomicAdd(out + (size_t)(rr + r) * O_DIM + cc, acc[mt][nt][r]);
        }
}

// ---------------------------------------------------------------------------
// Zero-workspace fallback: one block per batch row b. Basis staged in LDS,
// direct 5-coefficient gather from sc. Correct but slow; only taken if
// ws_size is too small for the GEMM path.
__global__ __launch_bounds__(256) void kan_fallback(const float* __restrict__ x,
                                                    const float* __restrict__ pw,
                                                    const float* __restrict__ bw,
                                                    const float* __restrict__ sw,
                                                    const float* __restrict__ sc,
                                                    float* __restrict__ out) {
    __shared__ float s_neg[J_DIM], s_pos[J_DIM], s_bas[J_DIM][5];
    __shared__ int s_k0[J_DIM];
    int b = blockIdx.x;
    int t = threadIdx.x;
#pragma unroll
    for (int jj = 0; jj < 2; ++jj) {
        int j = t + jj * 256;
        float xv = x[(size_t)b * J_DIM + j];
        float xc = fminf(fmaxf(xv, -1.f), 1.f);
        float pos = fmaxf(xc, 0.f);
        s_pos[j] = pos;
        s_neg[j] = xc - pos;
        int k0; float Nv[5];
        bspline5(xc, k0, Nv);
        s_k0[j] = k0;
#pragma unroll
        for (int r = 0; r < 5; ++r) s_bas[j][r] = Nv[r];
    }
    __syncthreads();
    for (int i = t; i < O_DIM; i += 256) {
        float acc = 0.f;
        for (int j = 0; j < J_DIM; ++j) {
            size_t ij = (size_t)i * J_DIM + j;
            float bwv = bw[ij];
            acc += bwv * (pw[ij] * s_neg[j] + s_pos[j]);
            int k0 = s_k0[j];
            const float* cp = sc + ij * 20;
            float sp = 0.f;
#pragma unroll
            for (int r = 0; r < 5; ++r) {
                int k = k0 + r;
                if (k >= 0) sp += s_bas[j][r] * cp[k];
            }
            acc += sw[ij] * sp;
        }
        out[(size_t)b * O_DIM + i] = acc;
    }
}

// ---------------------------------------------------------------------------
extern "C" void kernel_launch(void* const* d_in, const int* in_sizes, int n_in,
                              void* d_out, int out_size, void* d_ws, size_t ws_size,
                              hipStream_t stream) {
    const float* x  = (const float*)d_in[0];
    const float* pw = (const float*)d_in[1];
    const float* bw = (const float*)d_in[2];
    const float* sw = (const float*)d_in[3];
    const float* sc = (const float*)d_in[4];
    float* out = (float*)d_out;

    const size_t ws_needed = (size_t)(B_DIM + O_DIM) * K_TOT * sizeof(half_t); // 57.7 MB
    if (ws_size < ws_needed) {
        kan_fallback<<<B_DIM, 256, 0, stream>>>(x, pw, bw, sw, sc, out);
        return;
    }

    half_t* A  = (half_t*)d_ws;
    half_t* Ct = A + (size_t)B_DIM * K_TOT;

    prep_all<<<ZERO_BLKS + O_DIM + B_DIM, 256, 0, stream>>>(x, pw, bw, sw, sc, A, Ct, out);
    dim3 g(B_DIM / MTILE, O_DIM / NTILE, KSPLIT);   // (16, 4, 16)
    gemm_f16<<<g, 256, 0, stream>>>(A, Ct, out);
}

// Round 4
// 142.771 us; speedup vs baseline: 1.1178x; 1.1178x over previous
//
#include <hip/hip_runtime.h>

// KAN layer as one fused fp16 MFMA GEMM:
//   out[b,i] = sum_j [ neg*bw*pw + pos*bw + sum_k basis[b,j,k]*sw[i,j]*sc[i,j,k] ]
// A  [2048 x 11264] fp16 : per j, 22 slots = {20 basis (5 nonzero), neg, pos}
// Ct [ 512 x 11264] fp16 : per j, 22 slots = {sw*sc[0..19], bw*pw, bw}   (B^T layout)
// R4: KSPLIT=11 (KCH=32, atomics -30% vs R3), double-buffered LDS with ONE
//     barrier per chunk (load latency overlapped with previous chunk's MFMA),
//     prep_C sc reads as float4. Swizzle kept (R3: conflicts = 0).
// ws usage: A = 46.1 MB, Ct = 11.5 MB (57.7 MB total).

typedef _Float16 half_t;
typedef __attribute__((ext_vector_type(8))) _Float16 half8;
typedef __attribute__((ext_vector_type(4))) float floatx4;

#define B_DIM   2048
#define J_DIM   512
#define O_DIM   512
#define SLOTS   22
#define K_TOT   (J_DIM * SLOTS)      // 11264
#define MTILE   128
#define NTILE   128
#define BK      32
#define KSPLIT  11
#define KS_LEN  (K_TOT / KSPLIT)     // 1024
#define KCH     (KS_LEN / BK)        // 32
#define ZERO_BLKS 64                 // blocks zeroing the 4 MB output

// ---------------------------------------------------------------------------
// Quartic B-spline local basis, uniform knots g_i = -1.5 + i*(3.125/24).
// (Reference quirk: linspace(-1.5, 1.625, 25) -> spacing 3.125/24, NOT 0.125.)
// m in [3,19]; window k = m-4 .. m, entries with k<0 dropped.
__device__ __forceinline__ void bspline5(float xc, int& k0, float Nv[5]) {
    const float invS = 7.68f;              // 24/3.125 (exact ratio)
    float u = (xc + 1.5f) * invS;          // knot units
    int m = (int)u;
    m = min(max(m, 3), 19);
    k0 = m - 4;
    Nv[0] = 1.f; Nv[1] = 0.f; Nv[2] = 0.f; Nv[3] = 0.f; Nv[4] = 0.f;
#pragma unroll
    for (int d = 1; d <= 4; ++d) {
        float nw[5];
        float inv_d = 1.0f / (float)d;
#pragma unroll
        for (int r = 0; r < 5; ++r) {
            if (r > d) { nw[r] = 0.f; continue; }
            float kk = (float)(m - d + r);
            float acc = 0.f;
            if (r >= 1) acc += (u - kk) * Nv[r - 1];
            if (r < d)  acc += (kk + (float)(d + 1) - u) * Nv[r];
            nw[r] = acc * inv_d;
        }
#pragma unroll
        for (int r = 0; r < 5; ++r) Nv[r] = nw[r];
    }
}

// ---------------------------------------------------------------------------
// Fused prep: blocks [0,64) zero the output; [64, 64+512) build Ct rows;
// [64+512, 64+512+2048) build A rows.
__global__ __launch_bounds__(256) void prep_all(const float* __restrict__ x,
                                                const float* __restrict__ pw,
                                                const float* __restrict__ bw,
                                                const float* __restrict__ sw,
                                                const float* __restrict__ sc,
                                                half_t* __restrict__ A,
                                                half_t* __restrict__ Ct,
                                                float* __restrict__ out) {
    __shared__ half_t rec[J_DIM * SLOTS];  // 22528 B
    int bid = blockIdx.x;
    int t = threadIdx.x;

    if (bid < ZERO_BLKS) {
        float4* o = (float4*)out;
        int base = bid * 4096;
#pragma unroll
        for (int i = 0; i < 16; ++i)
            o[base + i * 256 + t] = make_float4(0.f, 0.f, 0.f, 0.f);
        return;
    }

    if (bid < ZERO_BLKS + O_DIM) {
        // prep_C: fold spline_weight into coeffs + base slots. sc row is
        // 16B-aligned per (i,j): ij*20 floats = ij*80 B.
        int i = bid - ZERO_BLKS;
#pragma unroll
        for (int jj = 0; jj < 2; ++jj) {
            int j = t + jj * 256;
            size_t ij = (size_t)i * J_DIM + j;
            float s = sw[ij], b = bw[ij], p = pw[ij];
            const float4* scp4 = (const float4*)(sc + ij * 20);
            half_t* r = rec + j * SLOTS;
#pragma unroll
            for (int v = 0; v < 5; ++v) {
                float4 c4 = scp4[v];
                r[v * 4 + 0] = (half_t)(s * c4.x);
                r[v * 4 + 1] = (half_t)(s * c4.y);
                r[v * 4 + 2] = (half_t)(s * c4.z);
                r[v * 4 + 3] = (half_t)(s * c4.w);
            }
            r[20] = (half_t)(b * p);
            r[21] = (half_t)b;
        }
        __syncthreads();
        const uint4* src = (const uint4*)rec;
        uint4* dst = (uint4*)(Ct + (size_t)i * K_TOT);
        for (int idx = t; idx < (J_DIM * SLOTS * 2) / 16; idx += 256) dst[idx] = src[idx];
        return;
    }

    // prep_A: basis record per (b, j)
    int b = bid - ZERO_BLKS - O_DIM;
#pragma unroll
    for (int jj = 0; jj < 2; ++jj) {
        int j = t + jj * 256;
        float xv = x[(size_t)b * J_DIM + j];
        float xc = fminf(fmaxf(xv, -1.f), 1.f);
        float pos = fmaxf(xc, 0.f);
        float neg = xc - pos;
        int k0; float Nv[5];
        bspline5(xc, k0, Nv);
        half_t* r = rec + j * SLOTS;
#pragma unroll
        for (int k = 0; k < 20; ++k) r[k] = (half_t)0.f;
#pragma unroll
        for (int rr = 0; rr < 5; ++rr) {
            int k = k0 + rr;
            if (k >= 0) r[k] = (half_t)Nv[rr];   // k <= 19 guaranteed (k0 <= 15)
        }
        r[20] = (half_t)neg;
        r[21] = (half_t)pos;
    }
    __syncthreads();
    const uint4* src = (const uint4*)rec;
    uint4* dst = (uint4*)(A + (size_t)b * K_TOT);
    for (int i = t; i < (J_DIM * SLOTS * 2) / 16; i += 256) dst[i] = src[i];
}

// ---------------------------------------------------------------------------
// GEMM: Grid (16, 4, 11) = (m-blocks, n-blocks, k-splits), 256 thr.
// Double-buffered LDS, ONE __syncthreads per chunk: at iter start the barrier
// (with its implicit vmcnt(0) drain) completes the loads issued LAST iter —
// which have had a full chunk of ds_read+MFMA to fly. XOR swizzle on the
// global source k-quad kills the 8-way fragment-read conflicts (R3: 0).
__global__ __launch_bounds__(256, 4) void gemm_f16(const half_t* __restrict__ A,
                                                   const half_t* __restrict__ Bt,
                                                   float* __restrict__ out) {
    __shared__ half_t As[2][MTILE * BK];   // 2 x 8 KB
    __shared__ half_t Bs[2][NTILE * BK];   // 2 x 8 KB

    int m0 = blockIdx.x * MTILE;
    int n0 = blockIdx.y * NTILE;
    int ks = blockIdx.z * KS_LEN;       // 1024*2 B: 16B-aligned

    int t = threadIdx.x;
    int w = t >> 6;          // wave 0..3
    int l = t & 63;
    int wm = w >> 1, wn = w & 1;

    floatx4 acc[4][4] = {};

    int lrow = l >> 2;                            // 0..15: row within 16-row chunk
    int lkof = (((l & 3) ^ ((l >> 3) & 3)) * 8);  // swizzled k-quad source offset

    const half_t* gA = A + (size_t)m0 * K_TOT + ks;
    const half_t* gB = Bt + (size_t)n0 * K_TOT + ks;

    int q = l >> 4;               // 0..3
    int fr = l & 15;              // 0..15
    int qs = (q ^ ((fr >> 1) & 3)) * 8;  // swizzled read offset (elements)

#define ISSUE_LOADS(c, p)                                                     \
    {                                                                         \
        int kb = (c) * BK;                                                    \
        _Pragma("unroll")                                                     \
        for (int n = 0; n < 2; ++n) {                                         \
            int r = (w * 2 + n) * 16 + lrow;                                  \
            __builtin_amdgcn_global_load_lds(                                 \
                (const __attribute__((address_space(1))) unsigned int*)       \
                    (gA + (size_t)r * K_TOT + kb + lkof),                     \
                (__attribute__((address_space(3))) unsigned int*)             \
                    (&As[p][0] + (w * 2 + n) * 512),                          \
                16, 0, 0);                                                    \
            __builtin_amdgcn_global_load_lds(                                 \
                (const __attribute__((address_space(1))) unsigned int*)       \
                    (gB + (size_t)r * K_TOT + kb + lkof),                     \
                (__attribute__((address_space(3))) unsigned int*)             \
                    (&Bs[p][0] + (w * 2 + n) * 512),                          \
                16, 0, 0);                                                    \
        }                                                                     \
    }

    ISSUE_LOADS(0, 0)
    int p = 0;
    for (int c = 0; c < KCH; ++c) {
        __syncthreads();                    // buf[p] complete (drains my loads)
        if (c + 1 < KCH) ISSUE_LOADS(c + 1, p ^ 1)  // fly during this chunk

        half8 af[4], bf[4];
#pragma unroll
        for (int mt = 0; mt < 4; ++mt)
            af[mt] = *(const half8*)(&As[p][0] + (wm * 64 + mt * 16 + fr) * BK + qs);
#pragma unroll
        for (int nt = 0; nt < 4; ++nt)
            bf[nt] = *(const half8*)(&Bs[p][0] + (wn * 64 + nt * 16 + fr) * BK + qs);
#pragma unroll
        for (int mt = 0; mt < 4; ++mt)
#pragma unroll
            for (int nt = 0; nt < 4; ++nt)
                acc[mt][nt] = __builtin_amdgcn_mfma_f32_16x16x32_f16(
                    af[mt], bf[nt], acc[mt][nt], 0, 0, 0);
        p ^= 1;
    }
#undef ISSUE_LOADS

    // epilogue: C/D layout col = lane&15, row = (lane>>4)*4 + reg (m89-verified)
#pragma unroll
    for (int mt = 0; mt < 4; ++mt)
#pragma unroll
        for (int nt = 0; nt < 4; ++nt) {
            int rr = m0 + wm * 64 + mt * 16 + q * 4;
            int cc = n0 + wn * 64 + nt * 16 + fr;
#pragma unroll
            for (int r = 0; r < 4; ++r)
                atomicAdd(out + (size_t)(rr + r) * O_DIM + cc, acc[mt][nt][r]);
        }
}

// ---------------------------------------------------------------------------
// Zero-workspace fallback (only if ws_size too small): correct but slow.
__global__ __launch_bounds__(256) void kan_fallback(const float* __restrict__ x,
                                                    const float* __restrict__ pw,
                                                    const float* __restrict__ bw,
                                                    const float* __restrict__ sw,
                                                    const float* __restrict__ sc,
                                                    float* __restrict__ out) {
    __shared__ float s_neg[J_DIM], s_pos[J_DIM], s_bas[J_DIM][5];
    __shared__ int s_k0[J_DIM];
    int b = blockIdx.x;
    int t = threadIdx.x;
#pragma unroll
    for (int jj = 0; jj < 2; ++jj) {
        int j = t + jj * 256;
        float xv = x[(size_t)b * J_DIM + j];
        float xc = fminf(fmaxf(xv, -1.f), 1.f);
        float pos = fmaxf(xc, 0.f);
        s_pos[j] = pos;
        s_neg[j] = xc - pos;
        int k0; float Nv[5];
        bspline5(xc, k0, Nv);
        s_k0[j] = k0;
#pragma unroll
        for (int r = 0; r < 5; ++r) s_bas[j][r] = Nv[r];
    }
    __syncthreads();
    for (int i = t; i < O_DIM; i += 256) {
        float acc = 0.f;
        for (int j = 0; j < J_DIM; ++j) {
            size_t ij = (size_t)i * J_DIM + j;
            float bwv = bw[ij];
            acc += bwv * (pw[ij] * s_neg[j] + s_pos[j]);
            int k0 = s_k0[j];
            const float* cp = sc + ij * 20;
            float sp = 0.f;
#pragma unroll
            for (int r = 0; r < 5; ++r) {
                int k = k0 + r;
                if (k >= 0) sp += s_bas[j][r] * cp[k];
            }
            acc += sw[ij] * sp;
        }
        out[(size_t)b * O_DIM + i] = acc;
    }
}

// ---------------------------------------------------------------------------
extern "C" void kernel_launch(void* const* d_in, const int* in_sizes, int n_in,
                              void* d_out, int out_size, void* d_ws, size_t ws_size,
                              hipStream_t stream) {
    const float* x  = (const float*)d_in[0];
    const float* pw = (const float*)d_in[1];
    const float* bw = (const float*)d_in[2];
    const float* sw = (const float*)d_in[3];
    const float* sc = (const float*)d_in[4];
    float* out = (float*)d_out;

    const size_t ws_needed = (size_t)(B_DIM + O_DIM) * K_TOT * sizeof(half_t); // 57.7 MB
    if (ws_size < ws_needed) {
        kan_fallback<<<B_DIM, 256, 0, stream>>>(x, pw, bw, sw, sc, out);
        return;
    }

    half_t* A  = (half_t*)d_ws;
    half_t* Ct = A + (size_t)B_DIM * K_TOT;

    prep_all<<<ZERO_BLKS + O_DIM + B_DIM, 256, 0, stream>>>(x, pw, bw, sw, sc, A, Ct, out);
    dim3 g(B_DIM / MTILE, O_DIM / NTILE, KSPLIT);   // (16, 4, 11)
    gemm_f16<<<g, 256, 0, stream>>>(A, Ct, out);
}